// Round 3
// baseline (403.359 us; speedup 1.0000x reference)
//
#include <hip/hip_runtime.h>

// mean_aggregator: out[b,:] = mean over s of emb[neighbors[b,s], :]
// B=50000, S=32, D=128. neighbors int32, emb float32, out float32.
//
// R3 design (fix: nontemporal store through native ext_vector float4 —
// __builtin_nontemporal_store rejects HIP_vector_type structs):
//   TWO output rows per 64-lane wave, float4 (16B) per lane.
//   - D = 128 floats = 512 B = 32 lanes x float4. Lanes 0-31 own row A,
//     lanes 32-63 own row B.
//   - Each gather instruction is a global_load_dwordx4 moving 1 KB/wave
//     (two random 512 B segments) -> half the VMEM instruction count and
//     2x the in-flight gather bytes per wave vs the R2 float2 version
//     (which delivered only ~2.05 TB/s vs the >6.3 TB/s pattern ceiling;
//     latency/issue-bound, not BW-bound).
//   - Both rows' neighbor indices stay wave-uniform -> scalar s_load path.
//     Per-half select is one v_cndmask per iteration; VALU had ~95%
//     headroom at R1/R2.
//   - Output is one contiguous 1 KB nontemporal store per wave (no reuse;
//     keep L2/IC space for the 256 MB gather-resident table).

#define AGG_BATCH 50000
#define AGG_S 32
#define AGG_D4 32              // 128 dims / 4 = 32 float4 chunks (one per half-wave lane)
#define AGG_WAVES_PER_BLOCK 4
#define AGG_ROWS_PER_BLOCK (AGG_WAVES_PER_BLOCK * 2)   // 2 rows per wave

typedef float floatx4 __attribute__((ext_vector_type(4)));  // native vector: valid
                                                            // for nontemporal builtin

__global__ __launch_bounds__(256) void mean_aggregator_49795850830175_kernel(
    const int* __restrict__ neighbors,
    const float4* __restrict__ emb,
    float4* __restrict__ out) {
  const int lane = threadIdx.x & 63;
  const int half = lane >> 5;        // 0: row A, 1: row B
  const int l4   = lane & 31;        // float4 index within the row

  int row0 = blockIdx.x * AGG_ROWS_PER_BLOCK + ((threadIdx.x >> 6) << 1);
  row0 = __builtin_amdgcn_readfirstlane(row0);   // wave-uniform pair base

  const int* __restrict__ nbA = neighbors + (size_t)row0 * AGG_S;  // rows A and B contiguous

  float4 acc;
  acc.x = 0.f; acc.y = 0.f; acc.z = 0.f; acc.w = 0.f;

#pragma unroll
  for (int s = 0; s < AGG_S; ++s) {
    const int ia = __builtin_amdgcn_readfirstlane(nbA[s]);          // scalar load, row A
    const int ib = __builtin_amdgcn_readfirstlane(nbA[AGG_S + s]);  // scalar load, row B
    const int idx = half ? ib : ia;                                 // v_cndmask per iter
    const float4 v = emb[(size_t)(unsigned)idx * AGG_D4 + l4];      // dwordx4 gather
    acc.x += v.x; acc.y += v.y; acc.z += v.z; acc.w += v.w;
  }

  const float inv = 1.0f / (float)AGG_S;
  floatx4 r;
  r.x = acc.x * inv; r.y = acc.y * inv; r.z = acc.z * inv; r.w = acc.w * inv;
  floatx4* outp = reinterpret_cast<floatx4*>(&out[((size_t)row0 + half) * AGG_D4 + l4]);
  __builtin_nontemporal_store(r, outp);
}

extern "C" void kernel_launch(void* const* d_in, const int* in_sizes, int n_in,
                              void* d_out, int out_size, void* d_ws, size_t ws_size,
                              hipStream_t stream) {
  const int* neighbors = (const int*)d_in[0];        // [B, S] int32
  const float4* emb = (const float4*)d_in[1];        // [N, D] fp32 as float4
  float4* out = (float4*)d_out;                      // [B, D] fp32 as float4

  const int grid = AGG_BATCH / AGG_ROWS_PER_BLOCK;   // 50000 % 8 == 0 -> 6250
  mean_aggregator_49795850830175_kernel<<<grid, 256, 0, stream>>>(neighbors, emb, out);
}

// Round 4
// 402.361 us; speedup vs baseline: 1.0025x; 1.0025x over previous
//
#include <hip/hip_runtime.h>

// mean_aggregator: out[b,:] = mean over s of emb[neighbors[b,s], :]
// B=50000, S=32, D=128. neighbors int32, emb float32, out float32.
//
// R4: single-variable experiment vs R3 (155 us kernel, 2.8 TB/s HBM,
// 5.5 TB/s delivered-to-CU, OccupancyPercent 57, VALUBusy 6.8).
//   R3 analysis: waves are queued on memory service rate (per-wave resident
//   time ~70K cycles vs ~3.6K if latency-bound), so more per-wave MLP is
//   useless. The only unexplained counter is occupancy=57% with NO resource
//   limit (VGPR 40, LDS 0) -> suspect per-CU workgroup-slot cap (~6 blocks
//   x 4 waves = 75% max resident). This round: 512-thread blocks (8 waves)
//   to double waves per block slot. Grid = 50000/16 = 3125 exactly.
//   Inner structure UNCHANGED for a clean A/B:
//   - 2 rows per 64-lane wave, float4 (16B) per lane; one dwordx4 gather
//     moves 1 KB/wave (two random 512B segments).
//   - Wave-uniform neighbor indices via readfirstlane -> scalar load path.
//   - Contiguous 1 KB nontemporal store per wave (don't pollute IC, the
//     256 MB table is IC-resident and supplies ~2.7 TB/s of hits).
// Decision rule: occupancy up + dur down -> queue slack existed, push more.
// Occupancy up + dur flat -> service-saturated; declare delivered-bytes
// roofline (851 MB / 6.3 TB/s = 135 us floor; R3 at 155 us = 87%).

#define AGG_BATCH 50000
#define AGG_S 32
#define AGG_D4 32              // 128 dims / 4 = 32 float4 chunks (one per half-wave lane)
#define AGG_WAVES_PER_BLOCK 8
#define AGG_ROWS_PER_BLOCK (AGG_WAVES_PER_BLOCK * 2)   // 2 rows per wave -> 16 rows/block

typedef float floatx4 __attribute__((ext_vector_type(4)));  // native vector: valid
                                                            // for nontemporal builtin

__global__ __launch_bounds__(512) void mean_aggregator_49795850830175_kernel(
    const int* __restrict__ neighbors,
    const float4* __restrict__ emb,
    float4* __restrict__ out) {
  const int lane = threadIdx.x & 63;
  const int half = lane >> 5;        // 0: row A, 1: row B
  const int l4   = lane & 31;        // float4 index within the row

  int row0 = blockIdx.x * AGG_ROWS_PER_BLOCK + ((threadIdx.x >> 6) << 1);
  row0 = __builtin_amdgcn_readfirstlane(row0);   // wave-uniform pair base

  const int* __restrict__ nbA = neighbors + (size_t)row0 * AGG_S;  // rows A and B contiguous

  float4 acc;
  acc.x = 0.f; acc.y = 0.f; acc.z = 0.f; acc.w = 0.f;

#pragma unroll
  for (int s = 0; s < AGG_S; ++s) {
    const int ia = __builtin_amdgcn_readfirstlane(nbA[s]);          // scalar load, row A
    const int ib = __builtin_amdgcn_readfirstlane(nbA[AGG_S + s]);  // scalar load, row B
    const int idx = half ? ib : ia;                                 // v_cndmask per iter
    const float4 v = emb[(size_t)(unsigned)idx * AGG_D4 + l4];      // dwordx4 gather
    acc.x += v.x; acc.y += v.y; acc.z += v.z; acc.w += v.w;
  }

  const float inv = 1.0f / (float)AGG_S;
  floatx4 r;
  r.x = acc.x * inv; r.y = acc.y * inv; r.z = acc.z * inv; r.w = acc.w * inv;
  floatx4* outp = reinterpret_cast<floatx4*>(&out[((size_t)row0 + half) * AGG_D4 + l4]);
  __builtin_nontemporal_store(r, outp);
}

extern "C" void kernel_launch(void* const* d_in, const int* in_sizes, int n_in,
                              void* d_out, int out_size, void* d_ws, size_t ws_size,
                              hipStream_t stream) {
  const int* neighbors = (const int*)d_in[0];        // [B, S] int32
  const float4* emb = (const float4*)d_in[1];        // [N, D] fp32 as float4
  float4* out = (float4*)d_out;                      // [B, D] fp32 as float4

  const int grid = AGG_BATCH / AGG_ROWS_PER_BLOCK;   // 50000 % 16 == 0 -> 3125
  mean_aggregator_49795850830175_kernel<<<grid, 512, 0, stream>>>(neighbors, emb, out);
}